// Round 7
// baseline (878.853 us; speedup 1.0000x reference)
//
#include <hip/hip_runtime.h>

#define N_NODES 12288
#define IN_F    256
#define OUT_F   64
#define KSPLIT  32
#define MT      64
#define KC      (N_NODES / KSPLIT)   /* 384 */
#define NSTRH   (N_NODES + 32)       /* hT row stride in shorts: 24640 B = 64 mod 4096 */
#define ABSTR   1600                 /* abits row stride in bytes (12288 bits = 1536 B + 64) */

typedef __attribute__((ext_vector_type(8))) short bf16x8;
typedef __attribute__((ext_vector_type(4))) float f32x4;

__device__ __forceinline__ unsigned short f2bf(float f) {
    union { float f; unsigned int i; } v; v.f = f;
    unsigned int x = v.i;
    unsigned int r = x + 0x7FFFu + ((x >> 16) & 1u);  // RNE
    return (unsigned short)(r >> 16);
}

// ---------------- kernel 0: adj int32 {0,1} -> bitmask (1 bit/entry, 19.7 MB).
// Linear 256B-per-instruction reads (the proven-fast shape), ballot per wave,
// lane 0 stores 8B. 2 rows per block, one half-row per wave.
__global__ __launch_bounds__(256) void k_bitpack(const int* __restrict__ adj,
                                                 unsigned char* __restrict__ abits) {
    const int tid  = threadIdx.x;
    const int lane = tid & 63;
    const int wave = tid >> 6;
    const int row  = blockIdx.x * 2 + (wave >> 1);
    const int half = wave & 1;

    const int* src = adj + (size_t)row * N_NODES + half * (N_NODES / 2) + lane;
    unsigned long long* dst =
        (unsigned long long*)(abits + (size_t)row * ABSTR + half * (N_NODES / 16));

    const int iters = (N_NODES / 2) / 64;   // 96
    int a0 = src[0];
    int a1 = src[64];
    for (int i = 0; i < iters - 2; ++i) {
        int a2 = src[(size_t)(i + 2) * 64];
        unsigned long long m = __ballot(a0 != 0);
        if (lane == 0) dst[i] = m;
        a0 = a1; a1 = a2;
    }
    unsigned long long m0 = __ballot(a0 != 0);
    unsigned long long m1 = __ballot(a1 != 0);
    if (lane == 0) { dst[iters - 2] = m0; dst[iters - 1] = m1; }
}

// ---------------- kernel 1: hT[n][i] = bf16( (x @ W)[i][n] ), padded row stride
__global__ __launch_bounds__(256) void k_hT(const float* __restrict__ x,
                                            const float* __restrict__ W,
                                            unsigned short* __restrict__ hT) {
    __shared__ unsigned short WT[OUT_F][IN_F + 8];   // WT[n][k] = bf16(W[k][n])
    int tid = threadIdx.x;
    for (int idx = tid; idx < IN_F * OUT_F; idx += 256) {
        int k = idx >> 6, n = idx & 63;
        WT[n][k] = f2bf(W[idx]);
    }
    __syncthreads();

    int lane = tid & 63, wave = tid >> 6;
    int q = lane >> 4, ml = lane & 15;
    int i0 = blockIdx.x * MT;
    int row = i0 + 16 * wave + ml;
    const float* xr = x + (size_t)row * IN_F + 8 * q;

    f32x4 acc[4];
    #pragma unroll
    for (int nt = 0; nt < 4; ++nt) acc[nt] = (f32x4){0.f, 0.f, 0.f, 0.f};

    #pragma unroll
    for (int kk = 0; kk < IN_F; kk += 32) {
        float4 x0 = *(const float4*)(xr + kk);
        float4 x1 = *(const float4*)(xr + kk + 4);
        union { bf16x8 v; unsigned short u[8]; } A;
        A.u[0] = f2bf(x0.x); A.u[1] = f2bf(x0.y); A.u[2] = f2bf(x0.z); A.u[3] = f2bf(x0.w);
        A.u[4] = f2bf(x1.x); A.u[5] = f2bf(x1.y); A.u[6] = f2bf(x1.z); A.u[7] = f2bf(x1.w);
        #pragma unroll
        for (int nt = 0; nt < 4; ++nt) {
            bf16x8 bv = *(const bf16x8*)&WT[16 * nt + ml][kk + 8 * q];
            acc[nt] = __builtin_amdgcn_mfma_f32_16x16x32_bf16(A.v, bv, acc[nt], 0, 0, 0);
        }
    }

    #pragma unroll
    for (int nt = 0; nt < 4; ++nt) {
        ushort4 o;
        o.x = f2bf(acc[nt][0]); o.y = f2bf(acc[nt][1]);
        o.z = f2bf(acc[nt][2]); o.w = f2bf(acc[nt][3]);
        *(ushort4*)&hT[(size_t)(16 * nt + ml) * NSTRH + i0 + 16 * wave + 4 * q] = o;
    }
}

// ---------------- kernel 2: bit-GEMM. Stage ONCE (B: 50 KB bf16; A: 3.3 KB bits),
// one barrier, then a pure LDS+VALU+MFMA inner loop: per step 1 ds_read_u8 +
// 4 ds_read_b128 + bit->bf16 expansion + 5 MFMA. Zero global loads in loop.
// Degree via ones-MFMA (exact, verified R4-R6).
__global__ __launch_bounds__(256) void k_spmm(const unsigned char* __restrict__ abits,
                                              const unsigned short* __restrict__ hT,
                                              float* __restrict__ s_part,
                                              float* __restrict__ deg_part) {
    __shared__ unsigned short Bs[OUT_F][KC + 8];   // 64 x 392 shorts = 50176 B
    __shared__ unsigned char  Ab[MT][52];          // 64 x 52 = 3328 B (48 used + pad)

    const int tid  = threadIdx.x;
    const int lane = tid & 63;
    const int wave = tid >> 6;
    const int q    = lane >> 4;
    const int ml   = lane & 15;
    const int i0   = blockIdx.x * MT;
    const int ks   = blockIdx.y;
    const int k0   = ks * KC;

    // ---- stage B: wave w covers rows 16w..16w+15; 4 lanes/row, 64B runs/row/instr
    {
        const int brow = 16 * wave + (lane >> 2);
        const int bco  = (lane & 3) * 8;            // shorts
        const unsigned short* bp = hT + (size_t)brow * NSTRH + k0 + bco;
        #pragma unroll
        for (int j = 0; j < 12; ++j) {
            uint4 v = *(const uint4*)(bp + 32 * j);
            *(uint4*)&Bs[brow][bco + 32 * j] = v;
        }
    }
    // ---- stage A bits: 64 rows x 48 B; thread t: row t>>2, 12 B chunk (t&3)
    {
        const int arow = tid >> 2;
        const int apart = (tid & 3) * 12;           // bytes
        const unsigned int* asrc =
            (const unsigned int*)(abits + (size_t)(i0 + arow) * ABSTR + ks * (KC / 8) + apart);
        unsigned int d0 = asrc[0], d1 = asrc[1], d2 = asrc[2];
        unsigned int* ad = (unsigned int*)&Ab[arow][apart];
        ad[0] = d0; ad[1] = d1; ad[2] = d2;
    }
    __syncthreads();

    union { bf16x8 v; unsigned short u[8]; } ones;
    #pragma unroll
    for (int i = 0; i < 8; ++i) ones.u[i] = 0x3F80;

    f32x4 acc[4], accd;
    #pragma unroll
    for (int nt = 0; nt < 4; ++nt) acc[nt] = (f32x4){0.f, 0.f, 0.f, 0.f};
    accd = (f32x4){0.f, 0.f, 0.f, 0.f};

    const int arow = 16 * wave + ml;
    #pragma unroll
    for (int kk = 0; kk < KC; kk += 32) {
        // A fragment: 8 bits -> 8 bf16 (elem j = bit j): per pair,
        // w = (b&1)*0x3F80 + (b&2)*0x1FC00000  (2*0x1FC00000 = 0x3F800000)
        unsigned int b = Ab[arow][(kk >> 3) + q];
        union { bf16x8 v; unsigned int w[4]; } av;
        av.w[0] = (b & 1u) * 0x3F80u         + (b & 2u) * 0x1FC00000u;
        av.w[1] = ((b >> 2) & 1u) * 0x3F80u  + ((b >> 2) & 2u) * 0x1FC00000u;
        av.w[2] = ((b >> 4) & 1u) * 0x3F80u  + ((b >> 4) & 2u) * 0x1FC00000u;
        av.w[3] = ((b >> 6) & 1u) * 0x3F80u  + ((b >> 6) & 2u) * 0x1FC00000u;

        #pragma unroll
        for (int nt = 0; nt < 4; ++nt) {
            bf16x8 bv = *(const bf16x8*)&Bs[16 * nt + ml][kk + 8 * q];
            acc[nt] = __builtin_amdgcn_mfma_f32_16x16x32_bf16(av.v, bv, acc[nt], 0, 0, 0);
        }
        accd = __builtin_amdgcn_mfma_f32_16x16x32_bf16(av.v, ones.v, accd, 0, 0, 0);
    }

    // epilogue: non-atomic partial store (each block owns its 64x64 region of slice ks)
    float* sp = s_part + (size_t)ks * ((size_t)N_NODES * OUT_F);
    #pragma unroll
    for (int nt = 0; nt < 4; ++nt) {
        #pragma unroll
        for (int rr = 0; rr < 4; ++rr) {
            int orow = i0 + 16 * wave + 4 * q + rr;   // C layout: row = quad*4+reg
            int ocol = 16 * nt + ml;                  // col = lane&15
            sp[(size_t)orow * OUT_F + ocol] = acc[nt][rr];
        }
    }

    // degree: C[m][n] of ones-MFMA is row-degree in every column; take col 0
    if (ml == 0) {
        #pragma unroll
        for (int rr = 0; rr < 4; ++rr)
            deg_part[ks * N_NODES + i0 + 16 * wave + 4 * q + rr] = accd[rr];
    }
}

// ---------------- kernel 3: out = elu( sum_p s_part / sum_p deg_part ), fp32
__global__ __launch_bounds__(256) void k_out(const float* __restrict__ s_part,
                                             const float* __restrict__ deg_part,
                                             float* __restrict__ out) {
    int idx = blockIdx.x * 256 + threadIdx.x;
    int i = idx >> 6;
    float s = 0.f, deg = 0.f;
    #pragma unroll
    for (int p = 0; p < KSPLIT; ++p) {
        s   += s_part[(size_t)p * ((size_t)N_NODES * OUT_F) + idx];
        deg += deg_part[p * N_NODES + i];
    }
    float v = (deg > 0.5f) ? (s / deg) : 0.f;
    out[idx] = (v > 0.f) ? v : expm1f(v);
}

extern "C" void kernel_launch(void* const* d_in, const int* in_sizes, int n_in,
                              void* d_out, int out_size, void* d_ws, size_t ws_size,
                              hipStream_t stream) {
    const int*   adj = (const int*)d_in[0];
    const float* x   = (const float*)d_in[1];   // fp32
    const float* W   = (const float*)d_in[2];   // fp32
    // d_in[3] (a) provably cancels out of the output — unused.
    float* out = (float*)d_out;                 // fp32

    char* ws = (char*)d_ws;
    const size_t hT_bytes = (size_t)OUT_F * NSTRH * 2;                   // ~1.58 MB
    const size_t sp_bytes = (size_t)KSPLIT * N_NODES * OUT_F * 4;        // 100.7 MB
    const size_t dp_bytes = (size_t)KSPLIT * N_NODES * 4;                // 1.6 MB
    unsigned short* hT   = (unsigned short*)ws;
    float* s_part        = (float*)(ws + hT_bytes);
    float* deg_part      = (float*)(ws + hT_bytes + sp_bytes);
    unsigned char* abits = (unsigned char*)(ws + hT_bytes + sp_bytes + dp_bytes);
    // abits: 12288 * 1600 B = 19.7 MB; total ~124 MB of d_ws (fill shows 2.4 GB)

    k_bitpack<<<dim3(N_NODES / 2),          dim3(256), 0, stream>>>(adj, abits);
    k_hT     <<<dim3(N_NODES / MT),         dim3(256), 0, stream>>>(x, W, hT);
    k_spmm   <<<dim3(N_NODES / MT, KSPLIT), dim3(256), 0, stream>>>(abits, hT, s_part, deg_part);
    k_out    <<<dim3(N_NODES * OUT_F / 256),dim3(256), 0, stream>>>(s_part, deg_part, out);
}

// Round 8
// 856.025 us; speedup vs baseline: 1.0267x; 1.0267x over previous
//
#include <hip/hip_runtime.h>

#define N_NODES 12288
#define IN_F    256
#define OUT_F   64
#define KSPLIT  32
#define MT      64
#define KC      (N_NODES / KSPLIT)   /* 384 */
#define NSTRH   (N_NODES + 32)       /* hT row stride in shorts: 24640 B = 64 mod 4096 */
#define ABSTR   (N_NODES / 8)        /* abits row stride bytes, UNPADDED: flat bit idx = flat int idx */

typedef __attribute__((ext_vector_type(8))) short bf16x8;
typedef __attribute__((ext_vector_type(4))) float f32x4;

__device__ __forceinline__ unsigned short f2bf(float f) {
    union { float f; unsigned int i; } v; v.f = f;
    unsigned int x = v.i;
    unsigned int r = x + 0x7FFFu + ((x >> 16) & 1u);  // RNE
    return (unsigned short)(r >> 16);
}

// ---------------- kernel 0: adj int32 {0,1} -> bitmask, k_pack-shaped.
// Grid-stride over the FLAT array: per iteration the whole chip sweeps ONE
// contiguous 8 MB window (2048 blocks x 4 KB); each wave ballots 4 consecutive
// 64-int groups (1 KB contiguous), double-buffered -> 8 loads / 32 B per lane
// in flight. lane 0 stores two ulonglong2 (32 B contiguous per wave-iter).
__global__ __launch_bounds__(256) void k_bitpack(const int* __restrict__ adj,
                                                 unsigned long long* __restrict__ abits) {
    const int tid  = threadIdx.x;
    const int lane = tid & 63;
    const int wave = tid >> 6;
    const int b    = blockIdx.x;          // 0..2047
    const int ITER = (N_NODES * N_NODES / 64) / (2048 * 16);   // 72

    // wave handles groups gbase(j) = (j*2048 + b)*16 + 4*wave + {0,1,2,3}
    const int* src0 = adj + ((size_t)b * 16 + 4 * wave) * 64 + lane;

    int curv[4], nxtv[4];
    #pragma unroll
    for (int g = 0; g < 4; ++g) curv[g] = src0[64 * g];

    for (int j = 0; j < ITER; ++j) {
        const size_t nb = ((size_t)(j + 1) * 2048) * 16 * 64;
        if (j + 1 < ITER) {
            #pragma unroll
            for (int g = 0; g < 4; ++g) nxtv[g] = src0[nb + 64 * g];
        }
        unsigned long long m0 = __ballot(curv[0] != 0);
        unsigned long long m1 = __ballot(curv[1] != 0);
        unsigned long long m2 = __ballot(curv[2] != 0);
        unsigned long long m3 = __ballot(curv[3] != 0);
        if (lane == 0) {
            unsigned long long* d = abits + ((size_t)j * 2048 + b) * 16 + 4 * wave;
            ((ulonglong2*)d)[0] = (ulonglong2){m0, m1};
            ((ulonglong2*)d)[1] = (ulonglong2){m2, m3};
        }
        #pragma unroll
        for (int g = 0; g < 4; ++g) curv[g] = nxtv[g];
    }
}

// ---------------- kernel 1: hT[n][i] = bf16( (x @ W)[i][n] ), padded row stride
__global__ __launch_bounds__(256) void k_hT(const float* __restrict__ x,
                                            const float* __restrict__ W,
                                            unsigned short* __restrict__ hT) {
    __shared__ unsigned short WT[OUT_F][IN_F + 8];   // WT[n][k] = bf16(W[k][n])
    int tid = threadIdx.x;
    for (int idx = tid; idx < IN_F * OUT_F; idx += 256) {
        int k = idx >> 6, n = idx & 63;
        WT[n][k] = f2bf(W[idx]);
    }
    __syncthreads();

    int lane = tid & 63, wave = tid >> 6;
    int q = lane >> 4, ml = lane & 15;
    int i0 = blockIdx.x * MT;
    int row = i0 + 16 * wave + ml;
    const float* xr = x + (size_t)row * IN_F + 8 * q;

    f32x4 acc[4];
    #pragma unroll
    for (int nt = 0; nt < 4; ++nt) acc[nt] = (f32x4){0.f, 0.f, 0.f, 0.f};

    #pragma unroll
    for (int kk = 0; kk < IN_F; kk += 32) {
        float4 x0 = *(const float4*)(xr + kk);
        float4 x1 = *(const float4*)(xr + kk + 4);
        union { bf16x8 v; unsigned short u[8]; } A;
        A.u[0] = f2bf(x0.x); A.u[1] = f2bf(x0.y); A.u[2] = f2bf(x0.z); A.u[3] = f2bf(x0.w);
        A.u[4] = f2bf(x1.x); A.u[5] = f2bf(x1.y); A.u[6] = f2bf(x1.z); A.u[7] = f2bf(x1.w);
        #pragma unroll
        for (int nt = 0; nt < 4; ++nt) {
            bf16x8 bv = *(const bf16x8*)&WT[16 * nt + ml][kk + 8 * q];
            acc[nt] = __builtin_amdgcn_mfma_f32_16x16x32_bf16(A.v, bv, acc[nt], 0, 0, 0);
        }
    }

    #pragma unroll
    for (int nt = 0; nt < 4; ++nt) {
        ushort4 o;
        o.x = f2bf(acc[nt][0]); o.y = f2bf(acc[nt][1]);
        o.z = f2bf(acc[nt][2]); o.w = f2bf(acc[nt][3]);
        *(ushort4*)&hT[(size_t)(16 * nt + ml) * NSTRH + i0 + 16 * wave + 4 * q] = o;
    }
}

// ---------------- kernel 2: bit-GEMM (R7-verified). Stage ONCE (B: 50 KB bf16,
// A: 3.3 KB bits), one barrier, pure LDS+VALU+MFMA inner loop.
// Degree via ones-MFMA (exact, verified R4-R7).
__global__ __launch_bounds__(256) void k_spmm(const unsigned char* __restrict__ abits,
                                              const unsigned short* __restrict__ hT,
                                              float* __restrict__ s_part,
                                              float* __restrict__ deg_part) {
    __shared__ unsigned short Bs[OUT_F][KC + 8];   // 64 x 392 shorts = 50176 B
    __shared__ unsigned char  Ab[MT][52];          // 64 x 52 = 3328 B (48 used + pad)

    const int tid  = threadIdx.x;
    const int lane = tid & 63;
    const int wave = tid >> 6;
    const int q    = lane >> 4;
    const int ml   = lane & 15;
    const int i0   = blockIdx.x * MT;
    const int ks   = blockIdx.y;
    const int k0   = ks * KC;

    // ---- stage B: wave w covers rows 16w..16w+15; 4 lanes/row, 64B runs/row/instr
    {
        const int brow = 16 * wave + (lane >> 2);
        const int bco  = (lane & 3) * 8;            // shorts
        const unsigned short* bp = hT + (size_t)brow * NSTRH + k0 + bco;
        #pragma unroll
        for (int j = 0; j < 12; ++j) {
            uint4 v = *(const uint4*)(bp + 32 * j);
            *(uint4*)&Bs[brow][bco + 32 * j] = v;
        }
    }
    // ---- stage A bits: 64 rows x 48 B; thread t: row t>>2, 12 B chunk (t&3)
    {
        const int arow = tid >> 2;
        const int apart = (tid & 3) * 12;           // bytes
        const unsigned int* asrc =
            (const unsigned int*)(abits + (size_t)(i0 + arow) * ABSTR + ks * (KC / 8) + apart);
        unsigned int d0 = asrc[0], d1 = asrc[1], d2 = asrc[2];
        unsigned int* ad = (unsigned int*)&Ab[arow][apart];
        ad[0] = d0; ad[1] = d1; ad[2] = d2;
    }
    __syncthreads();

    union { bf16x8 v; unsigned short u[8]; } ones;
    #pragma unroll
    for (int i = 0; i < 8; ++i) ones.u[i] = 0x3F80;

    f32x4 acc[4], accd;
    #pragma unroll
    for (int nt = 0; nt < 4; ++nt) acc[nt] = (f32x4){0.f, 0.f, 0.f, 0.f};
    accd = (f32x4){0.f, 0.f, 0.f, 0.f};

    const int arow = 16 * wave + ml;
    #pragma unroll
    for (int kk = 0; kk < KC; kk += 32) {
        // A fragment: 8 bits -> 8 bf16 (elem j = bit j): per pair,
        // w = (b&1)*0x3F80 + (b&2)*0x1FC00000  (2*0x1FC00000 = 0x3F800000)
        unsigned int b = Ab[arow][(kk >> 3) + q];
        union { bf16x8 v; unsigned int w[4]; } av;
        av.w[0] = (b & 1u) * 0x3F80u         + (b & 2u) * 0x1FC00000u;
        av.w[1] = ((b >> 2) & 1u) * 0x3F80u  + ((b >> 2) & 2u) * 0x1FC00000u;
        av.w[2] = ((b >> 4) & 1u) * 0x3F80u  + ((b >> 4) & 2u) * 0x1FC00000u;
        av.w[3] = ((b >> 6) & 1u) * 0x3F80u  + ((b >> 6) & 2u) * 0x1FC00000u;

        #pragma unroll
        for (int nt = 0; nt < 4; ++nt) {
            bf16x8 bv = *(const bf16x8*)&Bs[16 * nt + ml][kk + 8 * q];
            acc[nt] = __builtin_amdgcn_mfma_f32_16x16x32_bf16(av.v, bv, acc[nt], 0, 0, 0);
        }
        accd = __builtin_amdgcn_mfma_f32_16x16x32_bf16(av.v, ones.v, accd, 0, 0, 0);
    }

    // epilogue: non-atomic partial store (each block owns its 64x64 region of slice ks)
    float* sp = s_part + (size_t)ks * ((size_t)N_NODES * OUT_F);
    #pragma unroll
    for (int nt = 0; nt < 4; ++nt) {
        #pragma unroll
        for (int rr = 0; rr < 4; ++rr) {
            int orow = i0 + 16 * wave + 4 * q + rr;   // C layout: row = quad*4+reg
            int ocol = 16 * nt + ml;                  // col = lane&15
            sp[(size_t)orow * OUT_F + ocol] = acc[nt][rr];
        }
    }

    // degree: C[m][n] of ones-MFMA is row-degree in every column; take col 0
    if (ml == 0) {
        #pragma unroll
        for (int rr = 0; rr < 4; ++rr)
            deg_part[ks * N_NODES + i0 + 16 * wave + 4 * q + rr] = accd[rr];
    }
}

// ---------------- kernel 3: out = elu( sum_p s_part / sum_p deg_part ), fp32
__global__ __launch_bounds__(256) void k_out(const float* __restrict__ s_part,
                                             const float* __restrict__ deg_part,
                                             float* __restrict__ out) {
    int idx = blockIdx.x * 256 + threadIdx.x;
    int i = idx >> 6;
    float s = 0.f, deg = 0.f;
    #pragma unroll
    for (int p = 0; p < KSPLIT; ++p) {
        s   += s_part[(size_t)p * ((size_t)N_NODES * OUT_F) + idx];
        deg += deg_part[p * N_NODES + i];
    }
    float v = (deg > 0.5f) ? (s / deg) : 0.f;
    out[idx] = (v > 0.f) ? v : expm1f(v);
}

extern "C" void kernel_launch(void* const* d_in, const int* in_sizes, int n_in,
                              void* d_out, int out_size, void* d_ws, size_t ws_size,
                              hipStream_t stream) {
    const int*   adj = (const int*)d_in[0];
    const float* x   = (const float*)d_in[1];   // fp32
    const float* W   = (const float*)d_in[2];   // fp32
    // d_in[3] (a) provably cancels out of the output — unused.
    float* out = (float*)d_out;                 // fp32

    char* ws = (char*)d_ws;
    const size_t hT_bytes = (size_t)OUT_F * NSTRH * 2;                   // ~1.58 MB
    const size_t sp_bytes = (size_t)KSPLIT * N_NODES * OUT_F * 4;        // 100.7 MB
    const size_t dp_bytes = (size_t)KSPLIT * N_NODES * 4;                // 1.6 MB
    unsigned short* hT   = (unsigned short*)ws;
    float* s_part        = (float*)(ws + hT_bytes);
    float* deg_part      = (float*)(ws + hT_bytes + sp_bytes);
    unsigned char* abits = (unsigned char*)(ws + hT_bytes + sp_bytes + dp_bytes);
    // abits: 12288 * 1536 B = 18.9 MB (flat); total ~123 MB of d_ws

    k_bitpack<<<dim3(2048),                 dim3(256), 0, stream>>>(adj, (unsigned long long*)abits);
    k_hT     <<<dim3(N_NODES / MT),         dim3(256), 0, stream>>>(x, W, hT);
    k_spmm   <<<dim3(N_NODES / MT, KSPLIT), dim3(256), 0, stream>>>(abits, hT, s_part, deg_part);
    k_out    <<<dim3(N_NODES * OUT_F / 256),dim3(256), 0, stream>>>(s_part, deg_part, out);
}

// Round 9
// 820.933 us; speedup vs baseline: 1.0706x; 1.0427x over previous
//
#include <hip/hip_runtime.h>

#define N_NODES 12288
#define IN_F    256
#define OUT_F   64
#define KSPLIT  4
#define BK      64
#define MT      64
#define NSTRH   (N_NODES + 32)   /* hT row stride in shorts: 24640 B = 64 mod 4096 */

typedef __attribute__((ext_vector_type(8))) short bf16x8;
typedef __attribute__((ext_vector_type(4))) float f32x4;

__device__ __forceinline__ unsigned short f2bf(float f) {
    union { float f; unsigned int i; } v; v.f = f;
    unsigned int x = v.i;
    unsigned int r = x + 0x7FFFu + ((x >> 16) & 1u);  // RNE
    return (unsigned short)(r >> 16);
}

// ---------------- kernel 1: hT[n][i] = bf16( (x @ W)[i][n] ), padded row stride
__global__ __launch_bounds__(256) void k_hT(const float* __restrict__ x,
                                            const float* __restrict__ W,
                                            unsigned short* __restrict__ hT) {
    __shared__ unsigned short WT[OUT_F][IN_F + 8];   // WT[n][k] = bf16(W[k][n])
    int tid = threadIdx.x;
    for (int idx = tid; idx < IN_F * OUT_F; idx += 256) {
        int k = idx >> 6, n = idx & 63;
        WT[n][k] = f2bf(W[idx]);
    }
    __syncthreads();

    int lane = tid & 63, wave = tid >> 6;
    int q = lane >> 4, ml = lane & 15;
    int i0 = blockIdx.x * MT;
    int row = i0 + 16 * wave + ml;
    const float* xr = x + (size_t)row * IN_F + 8 * q;

    f32x4 acc[4];
    #pragma unroll
    for (int nt = 0; nt < 4; ++nt) acc[nt] = (f32x4){0.f, 0.f, 0.f, 0.f};

    #pragma unroll
    for (int kk = 0; kk < IN_F; kk += 32) {
        float4 x0 = *(const float4*)(xr + kk);
        float4 x1 = *(const float4*)(xr + kk + 4);
        union { bf16x8 v; unsigned short u[8]; } A;
        A.u[0] = f2bf(x0.x); A.u[1] = f2bf(x0.y); A.u[2] = f2bf(x0.z); A.u[3] = f2bf(x0.w);
        A.u[4] = f2bf(x1.x); A.u[5] = f2bf(x1.y); A.u[6] = f2bf(x1.z); A.u[7] = f2bf(x1.w);
        #pragma unroll
        for (int nt = 0; nt < 4; ++nt) {
            bf16x8 bv = *(const bf16x8*)&WT[16 * nt + ml][kk + 8 * q];
            acc[nt] = __builtin_amdgcn_mfma_f32_16x16x32_bf16(A.v, bv, acc[nt], 0, 0, 0);
        }
    }

    #pragma unroll
    for (int nt = 0; nt < 4; ++nt) {
        ushort4 o;
        o.x = f2bf(acc[nt][0]); o.y = f2bf(acc[nt][1]);
        o.z = f2bf(acc[nt][2]); o.w = f2bf(acc[nt][3]);
        *(ushort4*)&hT[(size_t)(16 * nt + ml) * NSTRH + i0 + 16 * wave + 4 * q] = o;
    }
}

// ---------------- kernel 2 (R0-proven structure, best measured @816):
// s_part[ks] = adj_slice @ h ; deg rowsum. Only change vs R0: padded hT stride.
__global__ __launch_bounds__(256) void k_spmm(const int* __restrict__ adj,
                                              const unsigned short* __restrict__ hT,
                                              float* __restrict__ s_part,
                                              int* __restrict__ deg_part) {
    // padded stride 72 (=8*9): keeps b128 alignment, rotates banks by 4/row
    __shared__ __align__(16) unsigned short As[64][72];   // adj tile as bf16 0/1
    __shared__ __align__(16) unsigned short Bs[64][72];   // Bs[n][k] = h[k][n]

    int tid  = threadIdx.x;
    int lane = tid & 63;
    int wave = tid >> 6;
    int q    = lane >> 4;       // quad 0..3
    int ml   = lane & 15;
    int i0   = blockIdx.x * MT;
    int ks   = blockIdx.y;
    int k0b  = ks * (N_NODES / KSPLIT);
    int r    = tid >> 2;        // staging row 0..63
    int cq   = (tid & 3) * 16;  // staging col chunk

    f32x4 acc[4];
    #pragma unroll
    for (int nt = 0; nt < 4; ++nt) acc[nt] = (f32x4){0.f, 0.f, 0.f, 0.f};
    int degacc = 0;

    const int iters = (N_NODES / KSPLIT) / BK;   // 48
    for (int it = 0; it < iters; ++it) {
        int k0 = k0b + it * BK;

        const int* ap = adj + (size_t)(i0 + r) * N_NODES + k0 + cq;
        int4 a0 = ((const int4*)ap)[0];
        int4 a1 = ((const int4*)ap)[1];
        int4 a2 = ((const int4*)ap)[2];
        int4 a3 = ((const int4*)ap)[3];

        const unsigned short* bp = hT + (size_t)r * NSTRH + k0 + cq;
        uint4 b01 = ((const uint4*)bp)[0];
        uint4 b23 = ((const uint4*)bp)[1];

        degacc += a0.x + a0.y + a0.z + a0.w;
        degacc += a1.x + a1.y + a1.z + a1.w;
        degacc += a2.x + a2.y + a2.z + a2.w;
        degacc += a3.x + a3.y + a3.z + a3.w;

        ushort4 c0, c1, c2, c3;
        c0.x = a0.x ? 0x3F80 : 0; c0.y = a0.y ? 0x3F80 : 0; c0.z = a0.z ? 0x3F80 : 0; c0.w = a0.w ? 0x3F80 : 0;
        c1.x = a1.x ? 0x3F80 : 0; c1.y = a1.y ? 0x3F80 : 0; c1.z = a1.z ? 0x3F80 : 0; c1.w = a1.w ? 0x3F80 : 0;
        c2.x = a2.x ? 0x3F80 : 0; c2.y = a2.y ? 0x3F80 : 0; c2.z = a2.z ? 0x3F80 : 0; c2.w = a2.w ? 0x3F80 : 0;
        c3.x = a3.x ? 0x3F80 : 0; c3.y = a3.y ? 0x3F80 : 0; c3.z = a3.z ? 0x3F80 : 0; c3.w = a3.w ? 0x3F80 : 0;

        *(ushort4*)&As[r][cq + 0]  = c0;
        *(ushort4*)&As[r][cq + 4]  = c1;
        *(ushort4*)&As[r][cq + 8]  = c2;
        *(ushort4*)&As[r][cq + 12] = c3;
        *(uint4*)&Bs[r][cq + 0] = b01;
        *(uint4*)&Bs[r][cq + 8] = b23;

        __syncthreads();

        #pragma unroll
        for (int kk = 0; kk < BK; kk += 32) {
            bf16x8 av = *(const bf16x8*)&As[16 * wave + ml][kk + 8 * q];
            #pragma unroll
            for (int nt = 0; nt < 4; ++nt) {
                bf16x8 bv = *(const bf16x8*)&Bs[16 * nt + ml][kk + 8 * q];
                acc[nt] = __builtin_amdgcn_mfma_f32_16x16x32_bf16(av, bv, acc[nt], 0, 0, 0);
            }
        }

        __syncthreads();
    }

    // epilogue: non-atomic partial store (each block owns its 64x64 region of slice ks)
    float* sp = s_part + (size_t)ks * ((size_t)N_NODES * OUT_F);
    #pragma unroll
    for (int nt = 0; nt < 4; ++nt) {
        #pragma unroll
        for (int rr = 0; rr < 4; ++rr) {
            int row = i0 + 16 * wave + 4 * q + rr;   // C layout: row = quad*4+reg
            int col = 16 * nt + ml;                  // col = lane&15
            sp[(size_t)row * OUT_F + col] = acc[nt][rr];
        }
    }

    degacc += __shfl_xor(degacc, 1, 64);
    degacc += __shfl_xor(degacc, 2, 64);
    if ((tid & 3) == 0)
        deg_part[ks * N_NODES + i0 + r] = degacc;
}

// ---------------- kernel 3: out = elu( sum_p s_part / sum_p deg_part ), fp32
__global__ __launch_bounds__(256) void k_out(const float* __restrict__ s_part,
                                             const int* __restrict__ deg_part,
                                             float* __restrict__ out) {
    int idx = blockIdx.x * 256 + threadIdx.x;
    int i = idx >> 6;
    float s = 0.f; int deg = 0;
    #pragma unroll
    for (int p = 0; p < KSPLIT; ++p) {
        s   += s_part[(size_t)p * ((size_t)N_NODES * OUT_F) + idx];
        deg += deg_part[p * N_NODES + i];
    }
    float v = (deg > 0) ? (s / (float)deg) : 0.f;
    out[idx] = (v > 0.f) ? v : expm1f(v);
}

extern "C" void kernel_launch(void* const* d_in, const int* in_sizes, int n_in,
                              void* d_out, int out_size, void* d_ws, size_t ws_size,
                              hipStream_t stream) {
    const int*   adj = (const int*)d_in[0];
    const float* x   = (const float*)d_in[1];   // fp32
    const float* W   = (const float*)d_in[2];   // fp32
    // d_in[3] (a) provably cancels out of the output — unused.
    float* out = (float*)d_out;                 // fp32

    char* ws = (char*)d_ws;
    const size_t hT_bytes = (size_t)OUT_F * NSTRH * 2;                   // ~1.58 MB
    const size_t sp_bytes = (size_t)KSPLIT * N_NODES * OUT_F * 4;        // 12.6 MB
    unsigned short* hT = (unsigned short*)ws;
    float* s_part      = (float*)(ws + hT_bytes);
    int*   deg_part    = (int*)(ws + hT_bytes + sp_bytes);
    // total ~14.3 MB of d_ws (harness-proven footprint)

    k_hT  <<<dim3(N_NODES / MT),          dim3(256), 0, stream>>>(x, W, hT);
    k_spmm<<<dim3(N_NODES / MT, KSPLIT),  dim3(256), 0, stream>>>(adj, hT, s_part, deg_part);
    k_out <<<dim3(N_NODES * OUT_F / 256), dim3(256), 0, stream>>>(s_part, deg_part, out);
}